// Round 4
// baseline (43122.626 us; speedup 1.0000x reference)
//
#include <hip/hip_runtime.h>
#include <hip/hip_bf16.h>
#include <math.h>

typedef __hip_bfloat16 bf16;

#define Bn   4
#define NF   64
#define Hn   192
#define Wn   192
#define HWn  (Hn*Wn)
#define OFFCH 216   // 3*DG*K
#define SAMPN 576   // NF*9

__device__ __forceinline__ float b2f(bf16 v){ return __bfloat162float(v); }
__device__ __forceinline__ bf16 f2b(float v){ return __float2bfloat16(v); }

// Runtime-dtype load: f32 != 0 -> fp32 buffer, else bf16 buffer.
__device__ __forceinline__ float ld(const void* p, size_t i, int f32){
    if (f32) return ((const float*)p)[i];
    return b2f(((const bf16*)p)[i]);
}

struct P20 { const void* p[20]; int n[20]; };

// ---------------------------------------------------------------------------
// Dtype probe: decode first <=512 uint16 of each input as bf16; if any value
// is huge/NaN/Inf, the buffer must be fp32 (mantissa halves decode garbage).
// All-zero buffers (biases) flag as bf16; zeros read identically either way.
// ---------------------------------------------------------------------------
__global__ void detect_kernel(P20 a, int* __restrict__ flags){
    int t = threadIdx.x;
    if (t >= 20) return;
    const unsigned short* u = (const unsigned short*)a.p[t];
    int n = a.n[t]; if (n > 512) n = 512;
    int f32 = 0;
    for (int i = 0; i < n; ++i) {
        float v = __uint_as_float(((unsigned)u[i]) << 16);
        if (!(fabsf(v) < 1e3f)) f32 = 1;   // catches big, Inf, NaN
    }
    flags[t] = f32;
}

// ---------------------------------------------------------------------------
// Direct 3x3 conv, pad=1, stride=1, optional channel-concat second input.
// 4 output channels per thread, one pixel per thread. Output always bf16
// (workspace scratch).
// ---------------------------------------------------------------------------
__global__ __launch_bounds__(256)
void conv3x3_kernel(const void* __restrict__ inA,
                    const void* __restrict__ inB,
                    const void* __restrict__ w,     // [64][CinT][3][3]
                    const void* __restrict__ bias,  // [64]
                    bf16* __restrict__ out,         // [B][64][H][W]
                    int CinA, int CinB, int ACT,
                    const int* __restrict__ flags,
                    int fiA, int fiB, int fiW, int fiBias)
{
    const int fA  = (fiA   >= 0) ? flags[fiA]   : 0;
    const int fB  = (fiB   >= 0) ? flags[fiB]   : 0;
    const int fW  = (fiW   >= 0) ? flags[fiW]   : 0;
    const int fBi = (fiBias>= 0) ? flags[fiBias]: 0;

    const int pix    = blockIdx.x * 256 + threadIdx.x;   // HW % 256 == 0
    const int ocBase = blockIdx.y * 4;
    const int b      = blockIdx.z;
    const int h      = pix / Wn;
    const int x      = pix - h * Wn;
    const int CinT   = CinA + CinB;

    int  offs[9];
    bool valid[9];
#pragma unroll
    for (int ky = 0; ky < 3; ++ky) {
        int yy = h + ky - 1;
        bool yv = (yy >= 0) && (yy < Hn);
#pragma unroll
        for (int kx = 0; kx < 3; ++kx) {
            int xx = x + kx - 1;
            bool v = yv && (xx >= 0) && (xx < Wn);
            valid[ky*3+kx] = v;
            offs[ky*3+kx]  = v ? ((ky-1)*Wn + (kx-1)) : 0;
        }
    }

    float acc[4];
#pragma unroll
    for (int i = 0; i < 4; ++i) acc[i] = ld(bias, ocBase + i, fBi);

    for (int seg = 0; seg < 2; ++seg) {
        const int cin = (seg == 0) ? CinA : CinB;
        if (cin == 0) continue;
        const void* src_t = (seg == 0) ? inA : inB;
        const int   fS    = (seg == 0) ? fA  : fB;
        const size_t base = (size_t)b * cin * HWn + pix;
        const int ci0 = (seg == 0) ? 0 : CinA;
        for (int ci = 0; ci < cin; ++ci) {
            const size_t sidx = base + (size_t)ci * HWn;
            float p[9];
#pragma unroll
            for (int k = 0; k < 9; ++k)
                p[k] = valid[k] ? ld(src_t, sidx + offs[k], fS) : 0.f;
            const size_t wrow = ((size_t)ocBase * CinT + (ci0 + ci)) * 9;
#pragma unroll
            for (int i = 0; i < 4; ++i) {
                const size_t wi = wrow + (size_t)i * (CinT * 9);
#pragma unroll
                for (int k = 0; k < 9; ++k)
                    acc[i] = fmaf(p[k], ld(w, wi + k, fW), acc[i]);
            }
        }
    }

#pragma unroll
    for (int i = 0; i < 4; ++i) {
        float v = acc[i];
        if (ACT) v = (v >= 0.f) ? v : 0.1f * v;
        out[((size_t)b * NF + ocBase + i) * HWn + pix] = f2b(v);
    }
}

// ---------------------------------------------------------------------------
// Fused DCN: 216-ch offset conv on `feat` + sigmoid(mask) + modulated
// deformable sampling of `x` + 64-ch projection. Block=256 thr, 4 pixels.
// outF32 selects final store dtype (fp32 for d_out, bf16 for scratch).
// ---------------------------------------------------------------------------
__device__ __forceinline__ float bl(const void* __restrict__ src, size_t cbase,
                                    int y, int x, int f32)
{
    if ((unsigned)y < (unsigned)Hn && (unsigned)x < (unsigned)Wn)
        return ld(src, cbase + y * Wn + x, f32);
    return 0.f;
}

__global__ __launch_bounds__(256)
void dcn_fused_kernel(const void* __restrict__ x,     // [B][64][H][W] sampled
                      const void* __restrict__ feat,  // [B][64][H][W] offconv in
                      const void* __restrict__ ow,    // [216][64][3][3]
                      const void* __restrict__ ob,    // [216]
                      const void* __restrict__ w,     // [64][64][3][3]
                      const void* __restrict__ bias,  // [64]
                      void* __restrict__ out,         // [B][64][H][W]
                      int ACT, int outF32,
                      const int* __restrict__ flags,
                      int fiX, int fiF, int fiOW, int fiOB, int fiW, int fiBias)
{
    const int fX  = (fiX   >= 0) ? flags[fiX]   : 0;
    const int fF  = (fiF   >= 0) ? flags[fiF]   : 0;
    const int fOW = (fiOW  >= 0) ? flags[fiOW]  : 0;
    const int fOB = (fiOB  >= 0) ? flags[fiOB]  : 0;
    const int fW  = (fiW   >= 0) ? flags[fiW]   : 0;
    const int fBi = (fiBias>= 0) ? flags[fiBias]: 0;

    __shared__ float s_patch[64][18];    // [ci][r*6+c]
    __shared__ float s_off[4][OFFCH];
    __shared__ float s_samp[4][SAMPN];

    const int b    = blockIdx.y;
    const int pix0 = blockIdx.x * 4;     // W % 4 == 0 -> same row
    const int tid  = threadIdx.x;
    const int h    = pix0 / Wn;
    const int x0   = pix0 - h * Wn;

    // Phase A0: stage 64ch x 3x6 patch of feat
    const size_t fbase = (size_t)b * NF * HWn;
    for (int idx = tid; idx < 64 * 18; idx += 256) {
        int ci = idx / 18;
        int rc = idx - ci * 18;
        int r  = rc / 6;
        int c  = rc - r * 6;
        int y  = h - 1 + r;
        int xx = x0 - 1 + c;
        float v = 0.f;
        if ((unsigned)y < (unsigned)Hn && (unsigned)xx < (unsigned)Wn)
            v = ld(feat, fbase + (size_t)ci * HWn + y * Wn + xx, fF);
        s_patch[ci][rc] = v;
    }
    __syncthreads();

    // Phase A1: 216-ch offset conv at the 4 pixels (thread = out channel)
    if (tid < OFFCH) {
        const size_t wr = (size_t)tid * 576;
        float a0 = ld(ob, tid, fOB);
        float a1 = a0, a2 = a0, a3 = a0;
        for (int ci = 0; ci < 64; ++ci) {
            const float* pr = s_patch[ci];
            const size_t wc = wr + ci * 9;
#pragma unroll
            for (int ky = 0; ky < 3; ++ky) {
#pragma unroll
                for (int kx = 0; kx < 3; ++kx) {
                    float wv = ld(ow, wc + ky * 3 + kx, fOW);
                    const float* prr = pr + ky * 6 + kx;
                    a0 = fmaf(prr[0], wv, a0);
                    a1 = fmaf(prr[1], wv, a1);
                    a2 = fmaf(prr[2], wv, a2);
                    a3 = fmaf(prr[3], wv, a3);
                }
            }
        }
        if (tid >= 144) {   // mask channels -> sigmoid
            a0 = 1.f / (1.f + expf(-a0));
            a1 = 1.f / (1.f + expf(-a1));
            a2 = 1.f / (1.f + expf(-a2));
            a3 = 1.f / (1.f + expf(-a3));
        }
        s_off[0][tid] = a0;
        s_off[1][tid] = a1;
        s_off[2][tid] = a2;
        s_off[3][tid] = a3;
    }
    __syncthreads();

    // Phase C: bilinear sampling -> s_samp[p][ci*9+k]
    for (int s = tid; s < 4 * SAMPN; s += 256) {
        int p  = s / SAMPN;
        int j  = s - p * SAMPN;
        int ci = j / 9;
        int k  = j - ci * 9;
        int dg = ci >> 3;
        int ky = k / 3;
        int kx = k - ky * 3;
        int xw = x0 + p;

        float dy = s_off[p][dg * 18 + k * 2];
        float dx = s_off[p][dg * 18 + k * 2 + 1];
        float m  = s_off[p][144 + dg * 9 + k];

        float py = dy + (float)(h - 1 + ky);
        float px = dx + (float)(xw - 1 + kx);
        float y0f = floorf(py), x0f = floorf(px);
        int   y0  = (int)y0f,   xi0 = (int)x0f;
        float wy  = py - y0f,   wx  = px - x0f;

        const size_t cbase = ((size_t)b * NF + ci) * HWn;
        float v00 = bl(x, cbase, y0,     xi0,     fX);
        float v01 = bl(x, cbase, y0,     xi0 + 1, fX);
        float v10 = bl(x, cbase, y0 + 1, xi0,     fX);
        float v11 = bl(x, cbase, y0 + 1, xi0 + 1, fX);
        float val = (1.f - wy) * (1.f - wx) * v00
                  + (1.f - wy) * wx         * v01
                  + wy         * (1.f - wx) * v10
                  + wy         * wx         * v11;
        s_samp[p][j] = val * m;
    }
    __syncthreads();

    // Phase D: 64 output channels x 4 pixels (thread = (p, oc))
    const int p   = tid >> 6;
    const int oc  = tid & 63;
    const int pix = pix0 + p;
    float acc = ld(bias, oc, fBi);
    const size_t wrow = (size_t)oc * SAMPN;
    const float* sp = s_samp[p];
    for (int j = 0; j < SAMPN; ++j)
        acc = fmaf(sp[j], ld(w, wrow + j, fW), acc);
    if (ACT) acc = (acc >= 0.f) ? acc : 0.1f * acc;
    const size_t oidx = ((size_t)b * NF + oc) * HWn + pix;
    if (outF32) ((float*)out)[oidx] = acc;
    else        ((bf16*) out)[oidx] = f2b(acc);
}

// ---------------------------------------------------------------------------
extern "C" void kernel_launch(void* const* d_in, const int* in_sizes, int n_in,
                              void* d_out, int out_size, void* d_ws, size_t ws_size,
                              hipStream_t stream)
{
    // Input indices per setup_inputs() order
    enum { I_NBR=0, I_REF=1, I_OC1W=2, I_OC1B=3, I_OC2W=4, I_OC2B=5,
           I_D1OW=6, I_D1OB=7, I_D1W=8, I_D1B=9, I_FCW=10, I_FCB=11,
           I_C1W=12, I_C1B=13, I_C2W=14, I_C2B=15, I_CDOW=16, I_CDOB=17,
           I_CDW=18, I_CDB=19 };

    // Workspace: [flags: 1 KB][buf1 bf16 64ch][buf2 bf16 64ch]
    int*  flags = (int*)d_ws;
    bf16* buf1  = (bf16*)((char*)d_ws + 1024);
    bf16* buf2  = buf1 + (size_t)Bn * NF * HWn;
    // d_out is fp32-sized (37.7 MB); its front half doubles as bf16 scratch
    // for intermediate feature maps (fully overwritten by the final store).
    bf16* bufA  = (bf16*)d_out;

    P20 a;
    for (int i = 0; i < 20; ++i) { a.p[i] = d_in[i]; a.n[i] = in_sizes[i]; }
    detect_kernel<<<1, 64, 0, stream>>>(a, flags);

    dim3 blk(256, 1, 1);
    dim3 g64(HWn / 256, NF / 4, Bn);   // (144, 16, 4)
    dim3 gD (HWn / 4,   Bn,     1);    // (9216, 4)

    // 1. t = lrelu(conv(cat(nbr, ref), oc1)) -> bufA
    conv3x3_kernel<<<g64, blk, 0, stream>>>(d_in[I_NBR], d_in[I_REF],
        d_in[I_OC1W], d_in[I_OC1B], bufA, NF, NF, 1, flags, I_NBR, I_REF, I_OC1W, I_OC1B);
    // 2. t = lrelu(conv(t, oc2)) -> buf1
    conv3x3_kernel<<<g64, blk, 0, stream>>>(bufA, nullptr,
        d_in[I_OC2W], d_in[I_OC2B], buf1, NF, 0, 1, flags, -1, -1, I_OC2W, I_OC2B);
    // 3. feat = dcn(x=nbr, offfeat=buf1; d1o fused) -> bufA (bf16 scratch)
    dcn_fused_kernel<<<gD, blk, 0, stream>>>(d_in[I_NBR], buf1,
        d_in[I_D1OW], d_in[I_D1OB], d_in[I_D1W], d_in[I_D1B], bufA, 0, 0,
        flags, I_NBR, -1, I_D1OW, I_D1OB, I_D1W, I_D1B);
    // 4. feat = conv(feat, fc) (no act) -> buf2
    conv3x3_kernel<<<g64, blk, 0, stream>>>(bufA, nullptr,
        d_in[I_FCW], d_in[I_FCB], buf2, NF, 0, 0, flags, -1, -1, I_FCW, I_FCB);
    // 5. t = lrelu(conv(cat(feat, ref), cas1)) -> bufA
    conv3x3_kernel<<<g64, blk, 0, stream>>>(buf2, d_in[I_REF],
        d_in[I_C1W], d_in[I_C1B], bufA, NF, NF, 1, flags, -1, I_REF, I_C1W, I_C1B);
    // 6. t = lrelu(conv(t, cas2)) -> buf1
    conv3x3_kernel<<<g64, blk, 0, stream>>>(bufA, nullptr,
        d_in[I_C2W], d_in[I_C2B], buf1, NF, 0, 1, flags, -1, -1, I_C2W, I_C2B);
    // 7. out = lrelu(dcn(x=buf2, offfeat=buf1; casd fused)) -> d_out (FP32)
    dcn_fused_kernel<<<gD, blk, 0, stream>>>(buf2, buf1,
        d_in[I_CDOW], d_in[I_CDOB], d_in[I_CDW], d_in[I_CDB], d_out, 1, 1,
        flags, -1, -1, I_CDOW, I_CDOB, I_CDW, I_CDB);
}

// Round 5
// 8142.049 us; speedup vs baseline: 5.2963x; 5.2963x over previous
//
#include <hip/hip_runtime.h>
#include <hip/hip_bf16.h>
#include <math.h>

typedef __hip_bfloat16 bf16;

#define Bn   4
#define NF   64
#define Hn   192
#define Wn   192
#define HWn  (Hn*Wn)
#define OFFCH 216
#define SAMPN 576
#define PX   16

// ---- fp32 workspace float-offsets (relative to F0 = ws+1024) ----
#define WF_OC1   0
#define WF_OC2   73728
#define WF_FC    110592
#define WF_CAS1  147456
#define WF_CAS2  221184
#define BIAS0    258048
#define B_OC1    (BIAS0+0)
#define B_OC2    (BIAS0+64)
#define B_FC     (BIAS0+128)
#define B_CAS1   (BIAS0+192)
#define B_CAS2   (BIAS0+256)
#define B_D1O    (BIAS0+320)
#define B_CDO    (BIAS0+536)
#define B_D1P    (BIAS0+752)
#define B_CDP    (BIAS0+816)
#define OWT_D1   258928
#define OWT_CD   383344
#define PWT_D1   507760
#define PWT_CD   544624
#define BUF1_OFF 2330624   // byte offset, 4K aligned, past float pool

__device__ __forceinline__ float b2f(bf16 v){ return __bfloat162float(v); }
__device__ __forceinline__ bf16 f2b(float v){ return __float2bfloat16(v); }
__device__ __forceinline__ float ld(const void* p, size_t i, int f32){
    if (f32) return ((const float*)p)[i];
    return b2f(((const bf16*)p)[i]);
}
__device__ __forceinline__ unsigned pack2(float a, float b){
    union { bf16 h[2]; unsigned u; } x;
    x.h[0] = f2b(a); x.h[1] = f2b(b);
    return x.u;
}

struct P20 { const void* p[20]; int n[20]; };

// ---------------------------------------------------------------------------
// Dtype probe (inputs proven fp32-in-memory; keep detection for robustness).
// ---------------------------------------------------------------------------
__global__ void detect_kernel(P20 a, int* __restrict__ flags){
    int t = threadIdx.x;
    if (t >= 20) return;
    const unsigned short* u = (const unsigned short*)a.p[t];
    int n = a.n[t]; if (n > 512) n = 512;
    int f32 = 0;
    for (int i = 0; i < n; ++i) {
        float v = __uint_as_float(((unsigned)u[i]) << 16);
        if (!(fabsf(v) < 1e3f)) f32 = 1;
    }
    flags[t] = f32;
}

// ---------------------------------------------------------------------------
// Prep: conv weights -> fp32 (original [O][Cin][9] layout)
// ---------------------------------------------------------------------------
__global__ void prep_convw(P20 a, const int* __restrict__ flags, float* __restrict__ F0){
    int i = blockIdx.x*256 + threadIdx.x;
    int srcIdx, base;
    if      (i < 73728)  { srcIdx=2;  base=0;      }
    else if (i < 110592) { srcIdx=4;  base=73728;  }
    else if (i < 147456) { srcIdx=10; base=110592; }
    else if (i < 221184) { srcIdx=12; base=147456; }
    else if (i < 258048) { srcIdx=14; base=221184; }
    else return;
    F0[i] = ld(a.p[srcIdx], i-base, flags[srcIdx]);
}

// ---------------------------------------------------------------------------
// Prep: DCN weights -> fp32 k-major transpose  dst[k][o] = src[o][k]
// ---------------------------------------------------------------------------
__global__ void prep_dcnw(P20 a, const int* __restrict__ flags, float* __restrict__ F0){
    int i = blockIdx.x*256 + threadIdx.x;
    int srcIdx, O, dst, rel;
    if      (i < 124416) { srcIdx=6;  O=216; dst=OWT_D1; rel=i; }
    else if (i < 248832) { srcIdx=16; O=216; dst=OWT_CD; rel=i-124416; }
    else if (i < 285696) { srcIdx=8;  O=64;  dst=PWT_D1; rel=i-248832; }
    else if (i < 322560) { srcIdx=18; O=64;  dst=PWT_CD; rel=i-285696; }
    else return;
    int o = rel / 576, k = rel - o*576;
    F0[dst + k*O + o] = ld(a.p[srcIdx], rel, flags[srcIdx]);
}

// ---------------------------------------------------------------------------
// Prep: all biases -> fp32 pool
// ---------------------------------------------------------------------------
__global__ void prep_bias(P20 a, const int* __restrict__ flags, float* __restrict__ F0){
    int t = threadIdx.x;
    const int src[9] = {3,5,11,13,15,7,17,9,19};
    const int sz[9]  = {64,64,64,64,64,216,216,64,64};
    int off = 0;
    for (int s = 0; s < 9; ++s){
        if (t < sz[s]) F0[BIAS0 + off + t] = ld(a.p[src[s]], t, flags[src[s]]);
        off += sz[s];
    }
}

// ---------------------------------------------------------------------------
// Direct 3x3 conv v2: 4 px x 4 oc register tile. Weights fp32 (prepped,
// wave-uniform -> scalar loads). Block=256 thr covers 1024 px.
// ---------------------------------------------------------------------------
__global__ __launch_bounds__(256)
void conv3x3_v2(const void* __restrict__ inA, const void* __restrict__ inB,
                const float* __restrict__ wf,   // [64][CinT][9] fp32
                const float* __restrict__ bfp,  // [64] fp32
                bf16* __restrict__ out,
                int CinA, int CinB, int ACT,
                const int* __restrict__ flags, int fiA, int fiB)
{
    const int fA = (fiA>=0)?flags[fiA]:0;
    const int fB = (fiB>=0)?flags[fiB]:0;
    const int px0 = blockIdx.x*1024 + threadIdx.x*4;   // 4 px, same row (W%4==0)
    const int ocBase = blockIdx.y*4;
    const int b = blockIdx.z;
    const int h = px0 / Wn;
    const int x0 = px0 - h*Wn;
    const int CinT = CinA + CinB;

    bool rv[3]; int roff[3];
#pragma unroll
    for (int r=0;r<3;++r){ int y=h-1+r; rv[r]=(unsigned)y<(unsigned)Hn; roff[r]=y*Wn; }
    bool cvld[6]; int coff[6];
#pragma unroll
    for (int c=0;c<6;++c){ int xx=x0-1+c; cvld[c]=(unsigned)xx<(unsigned)Wn; coff[c]=xx; }

    float acc[4][4];
#pragma unroll
    for (int i=0;i<4;++i){ float bv = bfp[ocBase+i];
#pragma unroll
        for(int p=0;p<4;++p) acc[i][p]=bv; }

    for (int seg=0; seg<2; ++seg){
        int cin = seg? CinB : CinA;
        if (!cin) continue;
        const void* src = seg? inB : inA;
        int fS = seg? fB : fA;
        int ci0 = seg? CinA : 0;
        size_t sbase = (size_t)b*cin*HWn;
        for (int ci=0; ci<cin; ++ci){
            size_t cb = sbase + (size_t)ci*HWn;
            float v[3][6];
#pragma unroll
            for (int r=0;r<3;++r)
#pragma unroll
                for (int c=0;c<6;++c)
                    v[r][c] = (rv[r]&&cvld[c]) ? ld(src, cb + roff[r] + coff[c], fS) : 0.f;
            const float* wr = wf + ((size_t)ocBase*CinT + ci0 + ci)*9;
#pragma unroll
            for (int i=0;i<4;++i){
                const float* wi = wr + (size_t)i*CinT*9;
#pragma unroll
                for (int ky=0;ky<3;++ky)
#pragma unroll
                    for (int kx=0;kx<3;++kx){
                        float wvv = wi[ky*3+kx];
#pragma unroll
                        for (int p=0;p<4;++p)
                            acc[i][p] = fmaf(v[ky][p+kx], wvv, acc[i][p]);
                    }
            }
        }
    }
#pragma unroll
    for (int i=0;i<4;++i)
#pragma unroll
        for (int p=0;p<4;++p){
            float vv = acc[i][p];
            if (ACT) vv = vv>=0.f? vv : 0.1f*vv;
            out[((size_t)b*NF+ocBase+i)*HWn + px0+p] = f2b(vv);
        }
}

// ---------------------------------------------------------------------------
// Fused DCN v2: 16 px/block. LDS: bf16-packed feat patch (3 shifted copies),
// fp32 offsets, bf16-packed samples. k-major fp32 weights (coalesced float4).
// ---------------------------------------------------------------------------
__device__ __forceinline__ float bl(const void* __restrict__ src, size_t cbase,
                                    int y, int x, int f32)
{
    if ((unsigned)y < (unsigned)Hn && (unsigned)x < (unsigned)Wn)
        return ld(src, cbase + y * Wn + x, f32);
    return 0.f;
}

__global__ __launch_bounds__(256)
void dcn_fused_v2(const void* __restrict__ x,     // sampled input
                  const bf16* __restrict__ feat,  // offset-conv input (bf16)
                  const float* __restrict__ owt,  // [576][216] k-major
                  const float* __restrict__ obf,  // [216]
                  const float* __restrict__ pwt,  // [576][64]  k-major
                  const float* __restrict__ pbf,  // [64]
                  void* __restrict__ out,
                  int ACT, int outF32,
                  const int* __restrict__ flags, int fiX)
{
    const int fX = (fiX>=0)?flags[fiX]:0;
    __shared__ unsigned s_patch[3*64*3*10];   // [sh][ci][ky][10] bf16 pairs (8 used)
    __shared__ float    s_off[216*17];        // [ch][17pad] -> px 0..15
    __shared__ unsigned s_samp[16*289];       // [px][289pad] bf16 pairs (288 used)

    const int b    = blockIdx.y;
    const int pix0 = blockIdx.x * PX;         // W%16==0 -> same row
    const int tid  = threadIdx.x;
    const int h    = pix0 / Wn;
    const int x0   = pix0 - h*Wn;

    // A0: stage 64ch x 3row x 18col patch as 3 shifted bf16-packed copies
    {
        const bf16* fb = feat + (size_t)b*NF*HWn;
        for (int idx = tid; idx < 3*64*3*8; idx += 256){
            int d  = idx & 7;
            int t  = idx >> 3;
            int ky = t % 3; t /= 3;
            int ci = t & 63;
            int sh = t >> 6;
            int y  = h-1+ky;
            int c0 = x0-1+sh + 2*d;
            float f0=0.f, f1=0.f;
            if ((unsigned)y < (unsigned)Hn){
                const bf16* row = fb + (size_t)ci*HWn + y*Wn;
                if ((unsigned)c0     < (unsigned)Wn) f0 = b2f(row[c0]);
                if ((unsigned)(c0+1) < (unsigned)Wn) f1 = b2f(row[c0+1]);
            }
            s_patch[((sh*64+ci)*3+ky)*10 + d] = pack2(f0,f1);
        }
    }
    __syncthreads();

    // A1: 216-ch offset conv, thread=(pxg,ocg), 4oc x 4px tile
    if (tid < 216){
        const int ocg = tid % 54;
        const int pxg = tid / 54;
        const int oc  = ocg*4;
        float acc[4][4];
        {
            float4 bv = *(const float4*)(obf + oc);
            float bb[4] = {bv.x,bv.y,bv.z,bv.w};
#pragma unroll
            for (int i=0;i<4;++i)
#pragma unroll
                for (int p=0;p<4;++p) acc[i][p]=bb[i];
        }
        int k = 0;
        for (int ci=0; ci<64; ++ci)
#pragma unroll
          for (int ky=0; ky<3; ++ky)
#pragma unroll
            for (int kx=0; kx<3; ++kx, ++k){
                const unsigned* pp = &s_patch[((kx*64+ci)*3+ky)*10 + 2*pxg];
                unsigned u0 = pp[0], u1 = pp[1];
                float v0 = __uint_as_float(u0<<16);
                float v1 = __uint_as_float(u0 & 0xffff0000u);
                float v2 = __uint_as_float(u1<<16);
                float v3 = __uint_as_float(u1 & 0xffff0000u);
                float4 wv = *(const float4*)(owt + (size_t)k*216 + oc);
                float ww[4] = {wv.x,wv.y,wv.z,wv.w};
#pragma unroll
                for (int i=0;i<4;++i){
                    acc[i][0]=fmaf(v0,ww[i],acc[i][0]);
                    acc[i][1]=fmaf(v1,ww[i],acc[i][1]);
                    acc[i][2]=fmaf(v2,ww[i],acc[i][2]);
                    acc[i][3]=fmaf(v3,ww[i],acc[i][3]);
                }
            }
        const bool sig = (oc >= 144);
#pragma unroll
        for (int i=0;i<4;++i)
#pragma unroll
            for (int p=0;p<4;++p){
                float vv = acc[i][p];
                if (sig) vv = 1.f/(1.f+expf(-vv));
                s_off[(oc+i)*17 + 4*pxg + p] = vv;
            }
    }
    __syncthreads();

    // C: bilinear sampling, bf16-pair packed into s_samp
    for (int it = tid; it < PX*288; it += 256){
        int px = it / 288;
        int q  = it - px*288;
        float sv[2];
#pragma unroll
        for (int e=0;e<2;++e){
            int j  = 2*q+e;
            int ci = j/9, k = j - ci*9;
            int dg = ci>>3;
            int ky = k/3, kx = k-ky*3;
            float dy = s_off[(dg*18+2*k  )*17 + px];
            float dx = s_off[(dg*18+2*k+1)*17 + px];
            float m  = s_off[(144+dg*9+k )*17 + px];
            float py  = dy + (float)(h-1+ky);
            float pxx = dx + (float)(x0+px-1+kx);
            float y0f=floorf(py), x0f=floorf(pxx);
            int y0=(int)y0f, xi0=(int)x0f;
            float wy=py-y0f, wx=pxx-x0f;
            size_t cb = ((size_t)b*NF+ci)*HWn;
            float v00 = bl(x, cb, y0,   xi0,   fX);
            float v01 = bl(x, cb, y0,   xi0+1, fX);
            float v10 = bl(x, cb, y0+1, xi0,   fX);
            float v11 = bl(x, cb, y0+1, xi0+1, fX);
            float val = (1.f-wy)*(1.f-wx)*v00 + (1.f-wy)*wx*v01
                      + wy*(1.f-wx)*v10 + wy*wx*v11;
            sv[e] = val*m;
        }
        s_samp[px*289 + q] = pack2(sv[0], sv[1]);
    }
    __syncthreads();

    // D: 64-ch projection, thread=(px, ocg), 4 oc per thread
    {
        const int ocg = tid & 15;
        const int px  = tid >> 4;
        const int oc  = ocg*4;
        float acc[4];
        { float4 bv = *(const float4*)(pbf+oc);
          acc[0]=bv.x;acc[1]=bv.y;acc[2]=bv.z;acc[3]=bv.w; }
        const unsigned* sp = &s_samp[px*289];
        for (int q=0; q<288; ++q){
            unsigned u = sp[q];
            float s0 = __uint_as_float(u<<16);
            float s1 = __uint_as_float(u & 0xffff0000u);
            int k = 2*q;
            float4 w0 = *(const float4*)(pwt + (size_t)k*64 + oc);
            float4 w1 = *(const float4*)(pwt + (size_t)(k+1)*64 + oc);
            acc[0]=fmaf(s0,w0.x,acc[0]); acc[1]=fmaf(s0,w0.y,acc[1]);
            acc[2]=fmaf(s0,w0.z,acc[2]); acc[3]=fmaf(s0,w0.w,acc[3]);
            acc[0]=fmaf(s1,w1.x,acc[0]); acc[1]=fmaf(s1,w1.y,acc[1]);
            acc[2]=fmaf(s1,w1.z,acc[2]); acc[3]=fmaf(s1,w1.w,acc[3]);
        }
        const int pix = pix0 + px;
#pragma unroll
        for (int i=0;i<4;++i){
            float vv = acc[i];
            if (ACT) vv = vv>=0.f? vv : 0.1f*vv;
            size_t oi = ((size_t)b*NF + oc+i)*HWn + pix;
            if (outF32) ((float*)out)[oi] = vv;
            else        ((bf16*) out)[oi] = f2b(vv);
        }
    }
}

// ---------------------------------------------------------------------------
extern "C" void kernel_launch(void* const* d_in, const int* in_sizes, int n_in,
                              void* d_out, int out_size, void* d_ws, size_t ws_size,
                              hipStream_t stream)
{
    enum { I_NBR=0, I_REF=1 };

    int*   flags = (int*)d_ws;
    float* F0    = (float*)((char*)d_ws + 1024);
    bf16*  buf1  = (bf16*)((char*)d_ws + BUF1_OFF);
    bf16*  buf2  = buf1 + (size_t)Bn * NF * HWn;
    bf16*  bufA  = (bf16*)d_out;    // fp32-sized; front half as bf16 scratch

    P20 a;
    for (int i = 0; i < 20; ++i) { a.p[i] = d_in[i]; a.n[i] = in_sizes[i]; }

    detect_kernel<<<1, 64, 0, stream>>>(a, flags);
    prep_convw<<<(258048+255)/256, 256, 0, stream>>>(a, flags, F0);
    prep_dcnw <<<(322560+255)/256, 256, 0, stream>>>(a, flags, F0);
    prep_bias <<<1, 256, 0, stream>>>(a, flags, F0);

    dim3 blk(256,1,1);
    dim3 gC(HWn/1024, 16, Bn);     // (36,16,4)
    dim3 gD(HWn/PX,   Bn, 1);      // (2304,4)

    // 1. t = lrelu(conv(cat(nbr,ref), oc1)) -> bufA
    conv3x3_v2<<<gC, blk, 0, stream>>>(d_in[I_NBR], d_in[I_REF],
        F0+WF_OC1, F0+B_OC1, bufA, NF, NF, 1, flags, I_NBR, I_REF);
    // 2. t = lrelu(conv(t, oc2)) -> buf1
    conv3x3_v2<<<gC, blk, 0, stream>>>(bufA, nullptr,
        F0+WF_OC2, F0+B_OC2, buf1, NF, 0, 1, flags, -1, -1);
    // 3. feat = dcn(x=nbr, offfeat=buf1) -> bufA (bf16)
    dcn_fused_v2<<<gD, blk, 0, stream>>>(d_in[I_NBR], buf1,
        F0+OWT_D1, F0+B_D1O, F0+PWT_D1, F0+B_D1P, bufA, 0, 0, flags, I_NBR);
    // 4. feat = conv(feat, fc) -> buf2
    conv3x3_v2<<<gC, blk, 0, stream>>>(bufA, nullptr,
        F0+WF_FC, F0+B_FC, buf2, NF, 0, 0, flags, -1, -1);
    // 5. t = lrelu(conv(cat(feat,ref), cas1)) -> bufA
    conv3x3_v2<<<gC, blk, 0, stream>>>(buf2, d_in[I_REF],
        F0+WF_CAS1, F0+B_CAS1, bufA, NF, NF, 1, flags, -1, I_REF);
    // 6. t = lrelu(conv(t, cas2)) -> buf1
    conv3x3_v2<<<gC, blk, 0, stream>>>(bufA, nullptr,
        F0+WF_CAS2, F0+B_CAS2, buf1, NF, 0, 1, flags, -1, -1);
    // 7. out = lrelu(dcn(x=buf2, offfeat=buf1)) -> d_out (fp32)
    dcn_fused_v2<<<gD, blk, 0, stream>>>(buf2, buf1,
        F0+OWT_CD, F0+B_CDO, F0+PWT_CD, F0+B_CDP, d_out, 1, 1, flags, -1);
}

// Round 7
// 2424.796 us; speedup vs baseline: 17.7840x; 3.3578x over previous
//
#include <hip/hip_runtime.h>
#include <hip/hip_bf16.h>
#include <math.h>

typedef __hip_bfloat16 bf16;
typedef float  floatx16 __attribute__((ext_vector_type(16)));
typedef short  short8   __attribute__((ext_vector_type(8)));

#define Bn 4
#define NF 64
#define Hn 192
#define Wn 192
#define HWn (Hn*Wn)

// ---- weight pool element offsets (bf16 elements, relative to WPOOL) ----
#define WA_OC1  0
#define WA_OC2  73728
#define WA_FC   110592
#define WA_CAS1 147456
#define WA_CAS2 221184
#define WA_D1O  258048
#define WA_CDO  405504
#define WP_D1   552960
#define WP_CD   589824
// ---- bias pool float offsets ----
#define B_OC1  0
#define B_OC2  64
#define B_FC   128
#define B_CAS1 192
#define B_CAS2 256
#define B_D1O  320
#define B_CDO  536
#define B_D1P  752
#define B_CDP  816
// ---- ws byte offsets ----
#define BIAS_OFF  1024
#define WPOOL_OFF 5120
#define BUF_OFF   1261568          // 4K aligned, past weight pool
#define FEAT_BYTES 18874368        // 4*64*36864*2

__device__ __forceinline__ float b2f(bf16 v){ return __bfloat162float(v); }
__device__ __forceinline__ bf16  f2b(float v){ return __float2bfloat16(v); }
__device__ __forceinline__ float ld(const void* p, size_t i, int f32){
    if (f32) return ((const float*)p)[i];
    return b2f(((const bf16*)p)[i]);
}

union B8 { uint2 u2[2]; uint4 u4; short8 s8; };

struct P20 { const void* p[20]; int n[20]; };

// ---------------------------------------------------------------------------
// Dtype probe (established: inputs fp32-in-memory, bf16-valued)
// ---------------------------------------------------------------------------
__global__ void detect_kernel(P20 a, int* __restrict__ flags){
    int t = threadIdx.x;
    if (t >= 20) return;
    const unsigned short* u = (const unsigned short*)a.p[t];
    int n = a.n[t]; if (n > 512) n = 512;
    int f32 = 0;
    for (int i = 0; i < n; ++i){
        float v = __uint_as_float(((unsigned)u[i]) << 16);
        if (!(fabsf(v) < 1e3f)) f32 = 1;
    }
    flags[t] = f32;
}

// ---------------------------------------------------------------------------
// Prep: 3x3 conv weights -> bf16 MFMA A-frag layout, tap-major K.
// dst[((ocb*9+tap)*KK + kk)*512 + m*16 + ko*8 + j] = w[ocb*32+m][kk*16+ko*8+j][tap]
// ---------------------------------------------------------------------------
__global__ void prep_convA(const void* __restrict__ src, const int* __restrict__ flags,
                           int fi, bf16* __restrict__ dst, int Cin, int CoutReal, int OCB)
{
    int idx = blockIdx.x*256 + threadIdx.x;
    int KK = Cin >> 4;
    int total = OCB*9*KK*512;
    if (idx >= total) return;
    int j  = idx & 7;
    int ko = (idx>>3) & 1;
    int m  = (idx>>4) & 31;
    int rest = idx >> 9;
    int kk = rest % KK; rest /= KK;
    int tap = rest % 9;
    int ocb = rest / 9;
    int oc = ocb*32 + m;
    int ci = kk*16 + ko*8 + j;
    float v = 0.f;
    if (oc < CoutReal) v = ld(src, ((size_t)oc*Cin + ci)*9 + tap, flags[fi]);
    dst[idx] = f2b(v);
}

// ---------------------------------------------------------------------------
// Prep: DCN projection weights -> A-frag layout, natural K = ci*9+tap (576).
// ---------------------------------------------------------------------------
__global__ void prep_projA(const void* __restrict__ src, const int* __restrict__ flags,
                           int fi, bf16* __restrict__ dst)
{
    int idx = blockIdx.x*256 + threadIdx.x;
    if (idx >= 2*36*512) return;
    int j  = idx & 7;
    int ko = (idx>>3) & 1;
    int m  = (idx>>4) & 31;
    int rest = idx >> 9;
    int kk = rest % 36;
    int ocb = rest / 36;
    int oc = ocb*32 + m;
    int k  = kk*16 + ko*8 + j;
    dst[idx] = f2b(ld(src, (size_t)oc*576 + k, flags[fi]));
}

// ---------------------------------------------------------------------------
// Prep: biases -> fp32 pool
// ---------------------------------------------------------------------------
__global__ void prep_bias(P20 a, const int* __restrict__ flags, float* __restrict__ bp){
    int t = threadIdx.x;
    const int src[9] = {3,5,11,13,15,7,17,9,19};
    const int off[9] = {B_OC1,B_OC2,B_FC,B_CAS1,B_CAS2,B_D1O,B_CDO,B_D1P,B_CDP};
    const int sz[9]  = {64,64,64,64,64,216,216,64,64};
    for (int s = 0; s < 9; ++s)
        if (t < sz[s]) bp[off[s] + t] = ld(a.p[src[s]], t, flags[src[s]]);
}

// ---------------------------------------------------------------------------
// MFMA implicit-GEMM 3x3 conv (pad=1). Block: 256 thr = 4 waves, tile 64oc x 64px.
// ACT: 0=none, 1=lrelu, 2=dcn-offset epilogue (sigmoid for oc>=144, raw below).
// ---------------------------------------------------------------------------
__global__ __launch_bounds__(256)
void conv_mfma(const void* __restrict__ inA, const void* __restrict__ inB,
               const bf16* __restrict__ wA, const float* __restrict__ bias,
               bf16* __restrict__ out,
               int CinA, int CinB, int CoutReal, int OutChStore, int ACT,
               const int* __restrict__ flags, int fiA, int fiB)
{
    extern __shared__ __align__(16) char smem_raw[];
    bf16* s_in = (bf16*)smem_raw;

    const int CinT  = CinA + CinB;
    const int ciPad = CinT + 4;                 // 68 or 132
    const int b     = blockIdx.z;
    const int pix0  = blockIdx.x * 64;          // 64 px, same row (192%64==0)
    const int h     = pix0 / Wn;
    const int x0    = pix0 - h*Wn;
    const int ocBase= blockIdx.y * 64;
    const int tid   = threadIdx.x;
    const int fA = (fiA>=0)?flags[fiA]:0;
    const int fB = (fiB>=0)?flags[fiB]:0;

    // ---- stage patch: rows h-1..h+1, cols x0-1..x0+64, all CinT channels ----
    const int total = 3*66*CinT;
    for (int idx = tid; idx < total; idx += 256){
        int c  = idx % 66;
        int r  = idx / 66;
        int ky = r % 3;
        int ci = r / 3;
        int y  = h - 1 + ky;
        int xx = x0 - 1 + c;
        float v = 0.f;
        if ((unsigned)y < (unsigned)Hn && (unsigned)xx < (unsigned)Wn){
            if (ci < CinA) v = ld(inA, ((size_t)b*CinA + ci)*HWn + y*Wn + xx, fA);
            else           v = ld(inB, ((size_t)b*CinB + (ci-CinA))*HWn + y*Wn + xx, fB);
        }
        s_in[(ky*66 + c)*ciPad + ci] = f2b(v);
    }
    __syncthreads();

    // ---- MFMA main loop ----
    const int w    = tid >> 6;
    const int lane = tid & 63;
    const int m    = lane & 31;
    const int half = lane >> 5;
    const int och  = (w >> 1) * 32;
    const int pxh  = (w & 1) * 32;
    const int KK   = CinT >> 4;
    const int ocb  = blockIdx.y*2 + (w >> 1);

    floatx16 acc;
#pragma unroll
    for (int r = 0; r < 16; ++r) acc[r] = 0.f;

    const bf16* wAb = wA + ((size_t)ocb*9*KK)*512 + m*16 + half*8;
    const int col0 = pxh + m;

#pragma unroll
    for (int tap = 0; tap < 9; ++tap){
        const int ky = tap/3, kx = tap - (tap/3)*3;
        const bf16* srow = s_in + (ky*66 + col0 + kx)*ciPad + half*8;
        for (int kk = 0; kk < KK; ++kk){
            B8 ba; ba.u4 = *(const uint4*)(wAb + (size_t)(tap*KK + kk)*512);
            B8 bb;
            const bf16* sp = srow + kk*16;
            bb.u2[0] = *(const uint2*)(sp);
            bb.u2[1] = *(const uint2*)(sp + 4);
            acc = __builtin_amdgcn_mfma_f32_32x32x16_bf16(ba.s8, bb.s8, acc, 0, 0, 0);
        }
    }

    // ---- epilogue ----
    const int pxo = pix0 + pxh + m;
#pragma unroll
    for (int r = 0; r < 16; ++r){
        int row = (r & 3) + 8*(r >> 2) + 4*half;
        int oc  = ocBase + och + row;
        if (oc < CoutReal){
            float v = acc[r] + bias[oc];
            if (ACT == 1) v = (v >= 0.f) ? v : 0.1f*v;
            else if (ACT == 2 && oc >= 144) v = 1.f/(1.f + expf(-v));  // mask sigmoid
            out[((size_t)b*OutChStore + oc)*HWn + pxo] = f2b(v);
        }
    }
}

// ---------------------------------------------------------------------------
// DCN sample + MFMA projection. Block: 256 thr, 64 px (one row segment).
// Phase C: (dg,tap)-outer loop — bilinear weights/indices computed once,
//          reused over the 8 channels of the group; masks are pre-sigmoided.
// Phase D: out[64oc][64px] = W(64x576) x samples via 32x32x16 MFMA.
// ---------------------------------------------------------------------------
__global__ __launch_bounds__(256)
void dcn_mfma(const void* __restrict__ x,      // sampled input [B][64][HW]
              const bf16* __restrict__ offs,   // [B][216][HW] bf16 (masks sigmoided)
              const bf16* __restrict__ wP,     // A-frag layout, K natural
              const float* __restrict__ pbias, // [64]
              void* __restrict__ out, int outF32, int ACT,
              const int* __restrict__ flags, int fiX)
{
    __shared__ bf16 s_samp[64*580];

    const int fX   = (fiX>=0)?flags[fiX]:0;
    const int b    = blockIdx.y;
    const int pix0 = blockIdx.x * 64;
    const int h    = pix0 / Wn;
    const int x0   = pix0 - h*Wn;
    const int tid  = threadIdx.x;

    // ---- Phase C: sampling ----
    {
        const int px = tid & 63;
        const int wq = tid >> 6;
        const size_t obase = (size_t)b*216*HWn + pix0 + px;
        const float fx = (float)(x0 + px - 1);
        for (int dt = wq*18; dt < wq*18 + 18; ++dt){   // (dg,tap) combos
            int dg  = dt / 9;
            int tap = dt - dg*9;
            int ky  = tap / 3;
            int kx  = tap - ky*3;
            float dy = b2f(offs[obase + (size_t)(dg*18 + tap*2    )*HWn]);
            float dx = b2f(offs[obase + (size_t)(dg*18 + tap*2 + 1)*HWn]);
            float mk = b2f(offs[obase + (size_t)(144 + dg*9 + tap )*HWn]);
            float py  = dy + (float)(h - 1 + ky);
            float pxx = dx + fx + (float)kx;
            float y0f = floorf(py), x0f = floorf(pxx);
            int   y0  = (int)y0f,   xi0 = (int)x0f;
            float wy  = py - y0f,   wx  = pxx - x0f;
            float w00 = (1.f-wy)*(1.f-wx)*mk, w01 = (1.f-wy)*wx*mk;
            float w10 = wy*(1.f-wx)*mk,       w11 = wy*wx*mk;
            bool y0v = (unsigned)y0     < (unsigned)Hn;
            bool y1v = (unsigned)(y0+1) < (unsigned)Hn;
            bool x0v = (unsigned)xi0     < (unsigned)Wn;
            bool x1v = (unsigned)(xi0+1) < (unsigned)Wn;
            int r0 = y0*Wn + xi0, r1 = r0 + Wn;
            size_t cb = ((size_t)b*NF + dg*8)*HWn;
#pragma unroll
            for (int cg = 0; cg < 8; ++cg){
                float v00 = (y0v&&x0v) ? ld(x, cb + r0,     fX) : 0.f;
                float v01 = (y0v&&x1v) ? ld(x, cb + r0 + 1, fX) : 0.f;
                float v10 = (y1v&&x0v) ? ld(x, cb + r1,     fX) : 0.f;
                float v11 = (y1v&&x1v) ? ld(x, cb + r1 + 1, fX) : 0.f;
                float val = w00*v00 + w01*v01 + w10*v10 + w11*v11;
                s_samp[px*580 + (dg*8 + cg)*9 + tap] = f2b(val);
                cb += HWn;
            }
        }
    }
    __syncthreads();

    // ---- Phase D: projection GEMM ----
    const int w    = tid >> 6;
    const int lane = tid & 63;
    const int m    = lane & 31;
    const int half = lane >> 5;
    const int och  = (w >> 1) * 32;
    const int pxh  = (w & 1) * 32;

    floatx16 acc;
#pragma unroll
    for (int r = 0; r < 16; ++r) acc[r] = 0.f;

    const bf16* wPb = wP + ((size_t)(w>>1)*36)*512 + m*16 + half*8;
    const bf16* srow = s_samp + (pxh + m)*580 + half*8;
#pragma unroll 4
    for (int kk = 0; kk < 36; ++kk){
        B8 ba; ba.u4 = *(const uint4*)(wPb + (size_t)kk*512);
        B8 bb;
        const bf16* sp = srow + kk*16;
        bb.u2[0] = *(const uint2*)(sp);
        bb.u2[1] = *(const uint2*)(sp + 4);
        acc = __builtin_amdgcn_mfma_f32_32x32x16_bf16(ba.s8, bb.s8, acc, 0, 0, 0);
    }

    const int pxo = pix0 + pxh + m;
#pragma unroll
    for (int r = 0; r < 16; ++r){
        int row = (r & 3) + 8*(r >> 2) + 4*half;
        int oc  = och + row;
        float v = acc[r] + pbias[oc];
        if (ACT) v = (v >= 0.f) ? v : 0.1f*v;
        size_t oi = ((size_t)b*NF + oc)*HWn + pxo;
        if (outF32) ((float*)out)[oi] = v;
        else        ((bf16*) out)[oi] = f2b(v);
    }
}

// ---------------------------------------------------------------------------
extern "C" void kernel_launch(void* const* d_in, const int* in_sizes, int n_in,
                              void* d_out, int out_size, void* d_ws, size_t ws_size,
                              hipStream_t stream)
{
    enum { I_NBR=0, I_REF=1, I_OC1W=2, I_OC2W=4, I_D1OW=6, I_D1W=8, I_FCW=10,
           I_C1W=12, I_C2W=14, I_CDOW=16, I_CDW=18 };

    int*   flags = (int*)d_ws;
    float* bp    = (float*)((char*)d_ws + BIAS_OFF);
    bf16*  wp    = (bf16*) ((char*)d_ws + WPOOL_OFF);
    bf16*  t1    = (bf16*) ((char*)d_ws + BUF_OFF);
    bf16*  f1    = (bf16*) ((char*)d_ws + BUF_OFF + FEAT_BYTES);
    bf16*  offs  = (bf16*) ((char*)d_ws + BUF_OFF + 2*(size_t)FEAT_BYTES);
    bf16*  t0    = (bf16*) d_out;   // fp32-sized out doubles as bf16 scratch

    P20 a;
    for (int i = 0; i < 20; ++i){ a.p[i] = d_in[i]; a.n[i] = in_sizes[i]; }

    detect_kernel<<<1, 64, 0, stream>>>(a, flags);
    prep_bias<<<1, 256, 0, stream>>>(a, flags, bp);
    prep_convA<<<288, 256, 0, stream>>>(d_in[I_OC1W], flags, I_OC1W, wp+WA_OC1, 128, 64, 2);
    prep_convA<<<144, 256, 0, stream>>>(d_in[I_OC2W], flags, I_OC2W, wp+WA_OC2,  64, 64, 2);
    prep_convA<<<144, 256, 0, stream>>>(d_in[I_FCW],  flags, I_FCW,  wp+WA_FC,   64, 64, 2);
    prep_convA<<<288, 256, 0, stream>>>(d_in[I_C1W],  flags, I_C1W,  wp+WA_CAS1,128, 64, 2);
    prep_convA<<<144, 256, 0, stream>>>(d_in[I_C2W],  flags, I_C2W,  wp+WA_CAS2, 64, 64, 2);
    prep_convA<<<576, 256, 0, stream>>>(d_in[I_D1OW], flags, I_D1OW, wp+WA_D1O,  64, 216, 8);
    prep_convA<<<576, 256, 0, stream>>>(d_in[I_CDOW], flags, I_CDOW, wp+WA_CDO,  64, 216, 8);
    prep_projA<<<144, 256, 0, stream>>>(d_in[I_D1W],  flags, I_D1W,  wp+WP_D1);
    prep_projA<<<144, 256, 0, stream>>>(d_in[I_CDW],  flags, I_CDW,  wp+WP_CD);

    dim3 blk(256,1,1);
    const int smem64  = 3*66*68*2;    // 26928 B
    const int smem128 = 3*66*132*2;   // 52272 B
    dim3 g64 (576, 1, Bn);
    dim3 g216(576, 4, Bn);
    dim3 gD  (576, Bn, 1);

    // 1. t0 = lrelu(conv(cat(nbr,ref), oc1))
    conv_mfma<<<g64, blk, smem128, stream>>>(d_in[I_NBR], d_in[I_REF], wp+WA_OC1, bp+B_OC1,
        t0, 64, 64, 64, 64, 1, flags, I_NBR, I_REF);
    // 2. t1 = lrelu(conv(t0, oc2))
    conv_mfma<<<g64, blk, smem64, stream>>>(t0, nullptr, wp+WA_OC2, bp+B_OC2,
        t1, 64, 0, 64, 64, 1, flags, -1, -1);
    // 3. offs = conv(t1, d1o)  [offsets raw, masks sigmoided via ACT=2]
    conv_mfma<<<g216, blk, smem64, stream>>>(t1, nullptr, wp+WA_D1O, bp+B_D1O,
        offs, 64, 0, 216, 216, 2, flags, -1, -1);
    // 4. t1 = dcn(x=nbr, offs; proj d1)
    dcn_mfma<<<gD, blk, 0, stream>>>(d_in[I_NBR], offs, wp+WP_D1, bp+B_D1P,
        t1, 0, 0, flags, I_NBR);
    // 5. f1 = conv(t1, fc)  (no act)
    conv_mfma<<<g64, blk, smem64, stream>>>(t1, nullptr, wp+WA_FC, bp+B_FC,
        f1, 64, 0, 64, 64, 0, flags, -1, -1);
    // 6. t0 = lrelu(conv(cat(f1, ref), cas1))
    conv_mfma<<<g64, blk, smem128, stream>>>(f1, d_in[I_REF], wp+WA_CAS1, bp+B_CAS1,
        t0, 64, 64, 64, 64, 1, flags, -1, I_REF);
    // 7. t1 = lrelu(conv(t0, cas2))
    conv_mfma<<<g64, blk, smem64, stream>>>(t0, nullptr, wp+WA_CAS2, bp+B_CAS2,
        t1, 64, 0, 64, 64, 1, flags, -1, -1);
    // 8. offs = conv(t1, cdo)  [ACT=2]
    conv_mfma<<<g216, blk, smem64, stream>>>(t1, nullptr, wp+WA_CDO, bp+B_CDO,
        offs, 64, 0, 216, 216, 2, flags, -1, -1);
    // 9. d_out = lrelu(dcn(x=f1, offs; proj cd))  fp32
    dcn_mfma<<<gD, blk, 0, stream>>>(f1, offs, wp+WP_CD, bp+B_CDP,
        d_out, 1, 1, flags, -1);
}